// Round 1
// baseline (2479.948 us; speedup 1.0000x reference)
//
#include <hip/hip_runtime.h>
#include <hip/hip_bf16.h>

// 2-layer tanh RNN. B=256, T=1024, H=128, V=96. x int32; float tensors
// runtime-detected fp32 vs bf16.
// d_in: 0:x 1:emb 2:W_ih0 3:W_hh0 4:b_ih0 5:b_hh0 6:W_ih1 7:W_hh1 8:b_ih1
//       9:b_hh1 10:fc_W 11:fc_b
// d_out: out[B*T,96] ++ hidden[2,B,128]
//
// MFMA rewrite: 16 blocks x 16 batches (batch = M dim of mfma_f32_16x16x32_bf16),
// 256 threads = 4 waves, each wave owns 2 x 16-col N-tiles. All weights held in
// registers as B-fragments, 3-term bf16 split (hi*hi + hi*lo + lo*hi) for
// fp32-equivalent accuracy through the 1024-step recurrence. 2 barriers/step.
// h' fragments read in phase B/C are register-carried into the next step.

#define B_SZ 256
#define T_LEN 1024
#define HD 128
#define VC 96
#define OUT_MAIN (B_SZ * T_LEN * VC)
#define HID_OFF OUT_MAIN

#define NB 16              // batches per block
#define NBLK (B_SZ / NB)   // 16 blocks
#define NT 256             // threads = 4 waves

typedef __attribute__((ext_vector_type(8))) short short8;
typedef __attribute__((ext_vector_type(4))) float f32x4;
static_assert(sizeof(short8) == 16, "short8 must be 16B");

__device__ __forceinline__ float bf2f(__hip_bfloat16 v) { return __bfloat162float(v); }

__device__ __forceinline__ bool detect_f32(const void* emb) {
  const unsigned short* u = (const unsigned short*)emb;
  int hits = 0;
#pragma unroll
  for (int i = 0; i < 128; ++i) hits += (((u[i] >> 7) & 0xFF) >= 127);
  return hits > 2;
}

__device__ __forceinline__ float ldw(const void* p, int i, bool f32) {
  return f32 ? ((const float*)p)[i] : bf2f(((const __hip_bfloat16*)p)[i]);
}

__device__ __forceinline__ float tanh_fast(float x) {
  float ax = fabsf(x);
  float e = __expf(-2.0f * ax);
  float y = 1.0f - 2.0f * __fdividef(e, 1.0f + e);
  return copysignf(y, x);
}

// bf16 RNE round to bits; values here are bounded (no NaN/Inf handling needed).
__device__ __forceinline__ unsigned short f2bfbits(float x) {
  unsigned u = __float_as_uint(x);
  unsigned r = (u + 0x7fffu + ((u >> 16) & 1u)) >> 16;
  return (unsigned short)r;
}
__device__ __forceinline__ float bfbits2f(unsigned short u) {
  return __uint_as_float((unsigned)u << 16);
}
__device__ __forceinline__ void bsplit(float x, unsigned short& hi, unsigned short& lo) {
  hi = f2bfbits(x);
  lo = f2bfbits(x - bfbits2f(hi));
}

// 3-term split-product MFMA: ACC += Ahi*Bhi + Ahi*Blo + Alo*Bhi  (~fp32 exact)
#define MM3(ACC, AH, AL, BH, BL)                                            \
  do {                                                                      \
    ACC = __builtin_amdgcn_mfma_f32_16x16x32_bf16(AH, BH, ACC, 0, 0, 0);    \
    ACC = __builtin_amdgcn_mfma_f32_16x16x32_bf16(AH, BL, ACC, 0, 0, 0);    \
    ACC = __builtin_amdgcn_mfma_f32_16x16x32_bf16(AL, BH, ACC, 0, 0, 0);    \
  } while (0)

__global__ __launch_bounds__(128) void embp_kernel(
    const void* __restrict__ emb, const void* __restrict__ Wih0,
    const void* __restrict__ bih0, const void* __restrict__ bhh0,
    float* __restrict__ embp) {
  const bool f32 = detect_f32(emb);
  __shared__ float ev[HD];
  const int v = blockIdx.x, r = threadIdx.x;
  ev[r] = ldw(emb, v * HD + r, f32);
  __syncthreads();
  float acc = ldw(bih0, r, f32) + ldw(bhh0, r, f32);
#pragma unroll 8
  for (int j = 0; j < HD; ++j) acc += ldw(Wih0, r * HD + j, f32) * ev[j];
  embp[v * HD + r] = acc;
}

// LDS h layout (per layer, hi/lo separate arrays of NB*HD bf16-bits):
//   element (batch m, hidden c) at index (c>>3)*128 + m*8 + (c&7)
// so A-fragment for lane (lm = m, lg = k-subchunk) of K-tile kt is the
// contiguous 8 elements at (kt*64 + lg*16 + lm)*8  -> one ds_read_b128.
template <bool USE_WS>
__global__ __launch_bounds__(NT, 1) void rnn_mfma(
    const int* __restrict__ x,
    const float* __restrict__ embp_g,
    const void* __restrict__ emb,
    const void* __restrict__ Wih0,
    const void* __restrict__ bih0,
    const void* __restrict__ bhh0,
    const void* __restrict__ Whh0,
    const void* __restrict__ Wih1,
    const void* __restrict__ Whh1,
    const void* __restrict__ bih1,
    const void* __restrict__ bhh1,
    const void* __restrict__ fcW,
    const void* __restrict__ fcb_g,
    void* __restrict__ out) {
  __shared__ __align__(16) float embp[VC * HD];            // 48 KB
  __shared__ __align__(16) unsigned short hb[4][NB * HD];  // 16 KB: h0hi,h0lo,h1hi,h1lo

  const int tid = threadIdx.x;
  const int lane = tid & 63;
  const int w = tid >> 6;    // wave 0..3
  const int lm = lane & 15;  // A-frag row (batch) / B-frag row (out col)
  const int lg = lane >> 4;  // k-subchunk 0..3
  const bool f32 = detect_f32(emb);
  const int bbase = blockIdx.x * NB;

  // ---- stage embp (input projection table) into LDS ----
  if constexpr (USE_WS) {
    const f32x4* src = (const f32x4*)embp_g;
    f32x4* dst = (f32x4*)embp;
#pragma unroll
    for (int i = 0; i < (VC * HD / 4) / NT; ++i) dst[tid + i * NT] = src[tid + i * NT];
  } else {
    const int r = tid & 127, vg = tid >> 7;  // vg 0..1
    const float bsum = ldw(bih0, r, f32) + ldw(bhh0, r, f32);
    for (int vi = 0; vi < 48; ++vi) {
      const int v = vg * 48 + vi;
      float acc = bsum;
#pragma unroll 8
      for (int k = 0; k < HD; ++k)
        acc += ldw(Wih0, r * HD + k, f32) * ldw(emb, v * HD + k, f32);
      embp[v * HD + r] = acc;
    }
  }

  // ---- per-lane column ownership ----
  const int c0 = 32 * w + lm;  // owned output col, tile 0
  const int c1 = c0 + 16;      // tile 1
  const bool fcact = (w < 3);  // FC cols 0..95 covered by waves 0..2

  // ---- weight B-fragments in registers (hi/lo split) ----
  short8 w0h[2][4], w0l[2][4];  // Whh0
  short8 wih[2][4], wil[2][4];  // Wih1
  short8 whh[2][4], whl[2][4];  // Whh1
  short8 wfh[2][4], wfl[2][4];  // fcW
#pragma unroll
  for (int tl = 0; tl < 2; ++tl) {
    const int n = c0 + 16 * tl;
#pragma unroll
    for (int kt = 0; kt < 4; ++kt) {
#pragma unroll
      for (int j = 0; j < 8; ++j) {
        const int k = kt * 32 + lg * 8 + j;
        unsigned short h, l;
        bsplit(ldw(Whh0, n * HD + k, f32), h, l);
        w0h[tl][kt][j] = (short)h; w0l[tl][kt][j] = (short)l;
        bsplit(ldw(Wih1, n * HD + k, f32), h, l);
        wih[tl][kt][j] = (short)h; wil[tl][kt][j] = (short)l;
        bsplit(ldw(Whh1, n * HD + k, f32), h, l);
        whh[tl][kt][j] = (short)h; whl[tl][kt][j] = (short)l;
        const float fv = fcact ? ldw(fcW, n * HD + k, f32) : 0.f;  // w=3 rows OOB -> guard
        bsplit(fv, h, l);
        wfh[tl][kt][j] = (short)h; wfl[tl][kt][j] = (short)l;
      }
    }
  }
  const float b1_0 = ldw(bih1, c0, f32) + ldw(bhh1, c0, f32);
  const float b1_1 = ldw(bih1, c1, f32) + ldw(bhh1, c1, f32);
  const float fcb0 = fcact ? ldw(fcb_g, c0, f32) : 0.f;
  const float fcb1 = fcact ? ldw(fcb_g, c1, f32) : 0.f;

  // LDS write bases for the lane's two owned columns
  const int wb0 = (c0 >> 3) * 128 + (c0 & 7);
  const int wb1 = (c1 >> 3) * 128 + (c1 & 7);

  // ---- carried h state fragments (zero-init: h_0 = 0) ----
  const short8 zero8 = {0, 0, 0, 0, 0, 0, 0, 0};
  short8 h0fh[4], h0fl[4], h1fh[4], h1fl[4];
#pragma unroll
  for (int kt = 0; kt < 4; ++kt) {
    h0fh[kt] = zero8; h0fl[kt] = zero8;
    h1fh[kt] = zero8; h1fl[kt] = zero8;
  }

  // token-id prefetch (one step ahead; hides global latency under compute)
  const int* xrow = x + bbase * T_LEN;
  int xid[4];
#pragma unroll
  for (int r = 0; r < 4; ++r) xid[r] = xrow[(lg * 4 + r) * T_LEN];

  __syncthreads();

  float* outf = (float*)out;
  __hip_bfloat16* outb = (__hip_bfloat16*)out;

  for (int t = 0; t < T_LEN; ++t) {
    // ---------- Phase A: h0' = tanh(embp[x_t] + Whh0 . h0) ----------
    float ep0[4], ep1[4];
#pragma unroll
    for (int r = 0; r < 4; ++r) {
      ep0[r] = embp[xid[r] * HD + c0];
      ep1[r] = embp[xid[r] * HD + c1];
    }
    if (t + 1 < T_LEN) {
#pragma unroll
      for (int r = 0; r < 4; ++r) xid[r] = xrow[(lg * 4 + r) * T_LEN + t + 1];
    }
    {
      f32x4 aA0 = {0.f, 0.f, 0.f, 0.f}, aB0 = {0.f, 0.f, 0.f, 0.f};
      f32x4 aA1 = {0.f, 0.f, 0.f, 0.f}, aB1 = {0.f, 0.f, 0.f, 0.f};
      MM3(aA0, h0fh[0], h0fl[0], w0h[0][0], w0l[0][0]);
      MM3(aA1, h0fh[0], h0fl[0], w0h[1][0], w0l[1][0]);
      MM3(aA0, h0fh[1], h0fl[1], w0h[0][1], w0l[0][1]);
      MM3(aA1, h0fh[1], h0fl[1], w0h[1][1], w0l[1][1]);
      MM3(aB0, h0fh[2], h0fl[2], w0h[0][2], w0l[0][2]);
      MM3(aB1, h0fh[2], h0fl[2], w0h[1][2], w0l[1][2]);
      MM3(aB0, h0fh[3], h0fl[3], w0h[0][3], w0l[0][3]);
      MM3(aB1, h0fh[3], h0fl[3], w0h[1][3], w0l[1][3]);
#pragma unroll
      for (int r = 0; r < 4; ++r) {
        const int m8 = (lg * 4 + r) * 8;
        unsigned short h, l;
        bsplit(tanh_fast(aA0[r] + aB0[r] + ep0[r]), h, l);
        hb[0][wb0 + m8] = h; hb[1][wb0 + m8] = l;
        bsplit(tanh_fast(aA1[r] + aB1[r] + ep1[r]), h, l);
        hb[0][wb1 + m8] = h; hb[1][wb1 + m8] = l;
      }
    }
    __syncthreads();  // bar1: h0' visible

    // ---------- Phase B: h1' = tanh(b1 + Wih1 . h0' + Whh1 . h1) ----------
#pragma unroll
    for (int kt = 0; kt < 4; ++kt) {
      const int rb = (kt * 64 + lg * 16 + lm) * 8;
      h0fh[kt] = *(const short8*)&hb[0][rb];  // carried into A(t+1)
      h0fl[kt] = *(const short8*)&hb[1][rb];
    }
    {
      f32x4 bA0 = {b1_0, b1_0, b1_0, b1_0}, bB0 = {0.f, 0.f, 0.f, 0.f};
      f32x4 bA1 = {b1_1, b1_1, b1_1, b1_1}, bB1 = {0.f, 0.f, 0.f, 0.f};
      MM3(bA0, h0fh[0], h0fl[0], wih[0][0], wil[0][0]);
      MM3(bA1, h0fh[0], h0fl[0], wih[1][0], wil[1][0]);
      MM3(bA0, h1fh[0], h1fl[0], whh[0][0], whl[0][0]);
      MM3(bA1, h1fh[0], h1fl[0], whh[1][0], whl[1][0]);
      MM3(bA0, h0fh[1], h0fl[1], wih[0][1], wil[0][1]);
      MM3(bA1, h0fh[1], h0fl[1], wih[1][1], wil[1][1]);
      MM3(bA0, h1fh[1], h1fl[1], whh[0][1], whl[0][1]);
      MM3(bA1, h1fh[1], h1fl[1], whh[1][1], whl[1][1]);
      MM3(bB0, h0fh[2], h0fl[2], wih[0][2], wil[0][2]);
      MM3(bB1, h0fh[2], h0fl[2], wih[1][2], wil[1][2]);
      MM3(bB0, h1fh[2], h1fl[2], whh[0][2], whl[0][2]);
      MM3(bB1, h1fh[2], h1fl[2], whh[1][2], whl[1][2]);
      MM3(bB0, h0fh[3], h0fl[3], wih[0][3], wil[0][3]);
      MM3(bB1, h0fh[3], h0fl[3], wih[1][3], wil[1][3]);
      MM3(bB0, h1fh[3], h1fl[3], whh[0][3], whl[0][3]);
      MM3(bB1, h1fh[3], h1fl[3], whh[1][3], whl[1][3]);
#pragma unroll
      for (int r = 0; r < 4; ++r) {
        const int m8 = (lg * 4 + r) * 8;
        unsigned short h, l;
        bsplit(tanh_fast(bA0[r] + bB0[r]), h, l);
        hb[2][wb0 + m8] = h; hb[3][wb0 + m8] = l;
        bsplit(tanh_fast(bA1[r] + bB1[r]), h, l);
        hb[2][wb1 + m8] = h; hb[3][wb1 + m8] = l;
      }
    }
    __syncthreads();  // bar2: h1' visible

    // ---------- Phase C: capture h1' frags (for B(t+1)) + FC output ----------
#pragma unroll
    for (int kt = 0; kt < 4; ++kt) {
      const int rb = (kt * 64 + lg * 16 + lm) * 8;
      h1fh[kt] = *(const short8*)&hb[2][rb];
      h1fl[kt] = *(const short8*)&hb[3][rb];
    }
    if (fcact) {
      f32x4 cA0 = {fcb0, fcb0, fcb0, fcb0}, cB0 = {0.f, 0.f, 0.f, 0.f};
      f32x4 cA1 = {fcb1, fcb1, fcb1, fcb1}, cB1 = {0.f, 0.f, 0.f, 0.f};
      MM3(cA0, h1fh[0], h1fl[0], wfh[0][0], wfl[0][0]);
      MM3(cA1, h1fh[0], h1fl[0], wfh[1][0], wfl[1][0]);
      MM3(cA0, h1fh[1], h1fl[1], wfh[0][1], wfl[0][1]);
      MM3(cA1, h1fh[1], h1fl[1], wfh[1][1], wfl[1][1]);
      MM3(cB0, h1fh[2], h1fl[2], wfh[0][2], wfl[0][2]);
      MM3(cB1, h1fh[2], h1fl[2], wfh[1][2], wfl[1][2]);
      MM3(cB0, h1fh[3], h1fl[3], wfh[0][3], wfl[0][3]);
      MM3(cB1, h1fh[3], h1fl[3], wfh[1][3], wfl[1][3]);
#pragma unroll
      for (int r = 0; r < 4; ++r) {
        const long row = ((long)(bbase + lg * 4 + r) * T_LEN + t) * VC;
        const float v0 = cA0[r] + cB0[r];
        const float v1 = cA1[r] + cB1[r];
        if (f32) {
          outf[row + c0] = v0; outf[row + c1] = v1;
        } else {
          outb[row + c0] = __float2bfloat16(v0); outb[row + c1] = __float2bfloat16(v1);
        }
      }
    }
    // no barrier here: A(t+1)'s hb[0/1] writes are ordered vs B(t)'s reads by
    // bar2(t); C(t)'s hb[2/3] reads are ordered vs B(t+1)'s writes by bar1(t+1).
  }

  // ---- final hidden state: wave 0's frags cover all (batch, k) ----
  if (w == 0) {
#pragma unroll
    for (int kt = 0; kt < 4; ++kt) {
#pragma unroll
      for (int j = 0; j < 8; ++j) {
        const int k = kt * 32 + lg * 8 + j;
        const float v0 = bfbits2f((unsigned short)h0fh[kt][j]) +
                         bfbits2f((unsigned short)h0fl[kt][j]);
        const float v1 = bfbits2f((unsigned short)h1fh[kt][j]) +
                         bfbits2f((unsigned short)h1fl[kt][j]);
        const long i0 = HID_OFF + (long)(bbase + lm) * HD + k;
        const long i1 = i0 + (long)B_SZ * HD;
        if (f32) {
          outf[i0] = v0; outf[i1] = v1;
        } else {
          outb[i0] = __float2bfloat16(v0); outb[i1] = __float2bfloat16(v1);
        }
      }
    }
  }
}

extern "C" void kernel_launch(void* const* d_in, const int* in_sizes, int n_in,
                              void* d_out, int out_size, void* d_ws, size_t ws_size,
                              hipStream_t stream) {
  const int* x = (const int*)d_in[0];
  const void* emb = d_in[1];
  const void* Wih0 = d_in[2];
  const void* Whh0 = d_in[3];
  const void* bih0 = d_in[4];
  const void* bhh0 = d_in[5];
  const void* Wih1 = d_in[6];
  const void* Whh1 = d_in[7];
  const void* bih1 = d_in[8];
  const void* bhh1 = d_in[9];
  const void* fcW = d_in[10];
  const void* fcb = d_in[11];

  const size_t need = (size_t)VC * HD * sizeof(float);
  if (d_ws != nullptr && ws_size >= need) {
    float* embp = (float*)d_ws;
    embp_kernel<<<VC, HD, 0, stream>>>(emb, Wih0, bih0, bhh0, embp);
    rnn_mfma<true><<<NBLK, NT, 0, stream>>>(x, embp, emb, Wih0, bih0, bhh0,
                                            Whh0, Wih1, Whh1, bih1, bhh1,
                                            fcW, fcb, d_out);
  } else {
    rnn_mfma<false><<<NBLK, NT, 0, stream>>>(x, nullptr, emb, Wih0, bih0, bhh0,
                                             Whh0, Wih1, Whh1, bih1, bhh1,
                                             fcW, fcb, d_out);
  }
}

// Round 2
// 1557.909 us; speedup vs baseline: 1.5918x; 1.5918x over previous
//
#include <hip/hip_runtime.h>
#include <hip/hip_bf16.h>

// 2-layer tanh RNN. B=256, T=1024, H=128, V=96. x int32; float tensors
// runtime-detected fp32 vs bf16.
// d_in: 0:x 1:emb 2:W_ih0 3:W_hh0 4:b_ih0 5:b_hh0 6:W_ih1 7:W_hh1 8:b_ih1
//       9:b_hh1 10:fc_W 11:fc_b
// d_out: out[B*T,96] ++ hidden[2,B,128]
//
// R2: fp16 single-term MFMA (error ~1.5e-4 << bf16 output-quantization floor),
// transposed orientation D = W.h^T (lane = batch): epilogue writes are 2x b64,
// ep gather is 2x float4 off one xid/lane, FC store is 2x 8B packed.
// Raw lgkmcnt-only barriers (no vmcnt drain of per-step output stores).
// 16 blocks x 16 batches, 256 threads = 4 waves, each wave owns 32 hidden cols.

#define B_SZ 256
#define T_LEN 1024
#define HD 128
#define VC 96
#define OUT_MAIN (B_SZ * T_LEN * VC)
#define HID_OFF OUT_MAIN

#define NB 16              // batches per block
#define NBLK (B_SZ / NB)   // 16 blocks
#define NT 256             // threads = 4 waves
#define EPW 132            // padded embp row stride (floats): bank-spread gather
#define HCH 136            // padded h chunk stride (fp16): 16 chunks of 8 cols

typedef _Float16 h8v __attribute__((ext_vector_type(8)));
typedef _Float16 h4v __attribute__((ext_vector_type(4)));
typedef float f4v __attribute__((ext_vector_type(4)));
typedef unsigned short us4v __attribute__((ext_vector_type(4)));

#define MM(A, Bf, C) __builtin_amdgcn_mfma_f32_16x16x32_f16(A, Bf, C, 0, 0, 0)

// LDS-only barrier: drain LDS ops, no vmcnt(0) drain (keeps global stores /
// token prefetch in flight across steps). Memory-clobber asms fence compiler
// motion of LDS ops; s_barrier builtin is convergent + side-effecting.
#define BARRIER()                                          \
  do {                                                     \
    asm volatile("s_waitcnt lgkmcnt(0)" ::: "memory");     \
    __builtin_amdgcn_s_barrier();                          \
    asm volatile("" ::: "memory");                         \
  } while (0)

__device__ __forceinline__ float bf2f(__hip_bfloat16 v) { return __bfloat162float(v); }

__device__ __forceinline__ bool detect_f32(const void* emb) {
  const unsigned short* u = (const unsigned short*)emb;
  int hits = 0;
#pragma unroll
  for (int i = 0; i < 128; ++i) hits += (((u[i] >> 7) & 0xFF) >= 127);
  return hits > 2;
}

__device__ __forceinline__ float ldw(const void* p, int i, bool f32) {
  return f32 ? ((const float*)p)[i] : bf2f(((const __hip_bfloat16*)p)[i]);
}

// tanh(x) = 1 - 2/(e^{2x}+1). Branch/NaN-free: x->+inf => 1, x->-inf => -1.
__device__ __forceinline__ float tanh_fast(float x) {
  float e = __expf(x + x);
  return 1.0f - __fdividef(2.0f, e + 1.0f);
}

// bf16 RNE round to bits (bounded values; no NaN handling needed).
__device__ __forceinline__ unsigned short f2bfbits(float x) {
  unsigned u = __float_as_uint(x);
  unsigned r = (u + 0x7fffu + ((u >> 16) & 1u)) >> 16;
  return (unsigned short)r;
}

__global__ __launch_bounds__(128) void embp_kernel(
    const void* __restrict__ emb, const void* __restrict__ Wih0,
    const void* __restrict__ bih0, const void* __restrict__ bhh0,
    float* __restrict__ embp) {
  const bool f32 = detect_f32(emb);
  __shared__ float ev[HD];
  const int v = blockIdx.x, r = threadIdx.x;
  ev[r] = ldw(emb, v * HD + r, f32);
  __syncthreads();
  float acc = ldw(bih0, r, f32) + ldw(bhh0, r, f32);
#pragma unroll 8
  for (int j = 0; j < HD; ++j) acc += ldw(Wih0, r * HD + j, f32) * ev[j];
  embp[v * HD + r] = acc;
}

// LDS h layout: element (batch m, hidden c) at chunk (c>>3)*HCH + m*8 + (c&7).
// Frag read (lane lm=m, lg=k-sub, tile kt): 16B at (kt*4+lg)*HCH + lm*8 —
// conflict-free b128. Epilogue (lane lm=batch) writes 4 consecutive c as b64.
template <bool USE_WS>
__global__ __launch_bounds__(NT) void rnn_mfma(
    const int* __restrict__ x,
    const float* __restrict__ embp_g,
    const void* __restrict__ emb,
    const void* __restrict__ Wih0,
    const void* __restrict__ bih0,
    const void* __restrict__ bhh0,
    const void* __restrict__ Whh0,
    const void* __restrict__ Wih1,
    const void* __restrict__ Whh1,
    const void* __restrict__ bih1,
    const void* __restrict__ bhh1,
    const void* __restrict__ fcW,
    const void* __restrict__ fcb_g,
    void* __restrict__ out) {
  __shared__ __align__(16) float embp[VC * EPW];       // 50688 B
  __shared__ __align__(16) _Float16 hb0[16 * HCH];     // 4352 B
  __shared__ __align__(16) _Float16 hb1[16 * HCH];     // 4352 B

  const int tid = threadIdx.x;
  const int lane = tid & 63;
  const int w = tid >> 6;    // wave 0..3: owns hidden cols 32w..32w+31
  const int lm = lane & 15;  // batch row (frags) / weight row (A-frags)
  const int lg = lane >> 4;  // k-subchunk 0..3
  const bool f32 = detect_f32(emb);
  const int bbase = blockIdx.x * NB;

  // ---- stage embp (input projection table), padded stride ----
  if constexpr (USE_WS) {
    const f4v* src = (const f4v*)embp_g;
#pragma unroll
    for (int i = 0; i < 12; ++i) {
      const int i4 = tid + i * NT;                    // f4 index over 96x32
      ((f4v*)embp)[(i4 >> 5) * 33 + (i4 & 31)] = src[i4];
    }
  } else {
    const int r = tid & 127, vg = tid >> 7;
    const float bsum = ldw(bih0, r, f32) + ldw(bhh0, r, f32);
    for (int vi = 0; vi < 48; ++vi) {
      const int v = vg * 48 + vi;
      float acc = bsum;
#pragma unroll 8
      for (int k = 0; k < HD; ++k)
        acc += ldw(Wih0, r * HD + k, f32) * ldw(emb, v * HD + k, f32);
      embp[v * EPW + r] = acc;
    }
  }

  const bool fcact = (w < 3);  // FC rows 0..95 on waves 0..2

  // ---- weight A-frags in registers (fp16, single term) ----
  // row n = 32w + 16*mt + lm, k = kt*32 + lg*8 + j
  h8v w0[2][4], wi[2][4], wh[2][4], wf[2][4];
#pragma unroll
  for (int mt = 0; mt < 2; ++mt) {
    const int n = 32 * w + 16 * mt + lm;
#pragma unroll
    for (int kt = 0; kt < 4; ++kt)
#pragma unroll
      for (int j = 0; j < 8; ++j) {
        const int k = kt * 32 + lg * 8 + j;
        w0[mt][kt][j] = (_Float16)ldw(Whh0, n * HD + k, f32);
        wi[mt][kt][j] = (_Float16)ldw(Wih1, n * HD + k, f32);
        wh[mt][kt][j] = (_Float16)ldw(Whh1, n * HD + k, f32);
        wf[mt][kt][j] = (_Float16)(fcact ? ldw(fcW, n * HD + k, f32) : 0.0f);
      }
  }
  // per-acc-element biases: acc[r] <-> hidden/vocab row c = 32w+16mt+4lg+r
  f4v b1v[2], fcv[2];
#pragma unroll
  for (int mt = 0; mt < 2; ++mt)
#pragma unroll
    for (int r = 0; r < 4; ++r) {
      const int c = 32 * w + 16 * mt + 4 * lg + r;
      b1v[mt][r] = ldw(bih1, c, f32) + ldw(bhh1, c, f32);
      fcv[mt][r] = fcact ? ldw(fcb_g, c, f32) : 0.0f;
    }

  // LDS offsets
  const int rd = lg * HCH + lm * 8;  // frag read base; + kt*4*HCH
  const int wofs0 = (4 * w + (lg >> 1)) * HCH + lm * 8 + 4 * (lg & 1);
  const int wofs1 = wofs0 + 2 * HCH;

  // carried h state fragments (zero-init: h_0 = 0)
  h8v h0f[4], h1f[4];
  const h8v hz = {0, 0, 0, 0, 0, 0, 0, 0};
#pragma unroll
  for (int kt = 0; kt < 4; ++kt) { h0f[kt] = hz; h1f[kt] = hz; }

  const int* xcol = x + (bbase + lm) * T_LEN;  // this lane's batch token stream

  __syncthreads();  // embp staged

  // prologue: ep(0)
  f4v epc[2];
  {
    const int xid0 = xcol[0];
    epc[0] = *(const f4v*)&embp[xid0 * EPW + 32 * w + 4 * lg];
    epc[1] = *(const f4v*)&embp[xid0 * EPW + 32 * w + 16 + 4 * lg];
  }

  float* outf = (float*)out;
  unsigned short* outu = (unsigned short*)out;

#pragma unroll 1
  for (int t = 0; t < T_LEN; ++t) {
    // ---------- Phase A: h0' = tanh(embp[x_t] + Whh0 . h0) ----------
    const int tn = (t + 1 < T_LEN) ? t + 1 : 0;
    const int xidn = xcol[tn];  // global load; consumed in C (gather for t+1)
    {
      f4v aA0 = epc[0], aA1 = epc[1];
      f4v aB0 = {0.f, 0.f, 0.f, 0.f}, aB1 = {0.f, 0.f, 0.f, 0.f};
      aA0 = MM(w0[0][0], h0f[0], aA0); aA1 = MM(w0[1][0], h0f[0], aA1);
      aA0 = MM(w0[0][1], h0f[1], aA0); aA1 = MM(w0[1][1], h0f[1], aA1);
      aB0 = MM(w0[0][2], h0f[2], aB0); aB1 = MM(w0[1][2], h0f[2], aB1);
      aB0 = MM(w0[0][3], h0f[3], aB0); aB1 = MM(w0[1][3], h0f[3], aB1);
      h4v p0, p1;
#pragma unroll
      for (int r = 0; r < 4; ++r) {
        p0[r] = (_Float16)tanh_fast(aA0[r] + aB0[r]);
        p1[r] = (_Float16)tanh_fast(aA1[r] + aB1[r]);
      }
      *(h4v*)&hb0[wofs0] = p0;
      *(h4v*)&hb0[wofs1] = p1;
    }
    BARRIER();  // bar1: h0' visible

    // ---------- Phase B: h1' = tanh(b1 + Wih1 . h0' + Whh1 . h1) ----------
    h0f[0] = *(const h8v*)&hb0[rd];
    h0f[1] = *(const h8v*)&hb0[rd + 4 * HCH];
    h0f[2] = *(const h8v*)&hb0[rd + 8 * HCH];
    h0f[3] = *(const h8v*)&hb0[rd + 12 * HCH];
    {
      f4v bA0 = b1v[0], bA1 = b1v[1];
      f4v bB0 = {0.f, 0.f, 0.f, 0.f}, bB1 = {0.f, 0.f, 0.f, 0.f};
      // Whh1 on carried h1 frags first (pure-reg: hides h0' read latency)
      bA0 = MM(wh[0][0], h1f[0], bA0); bA1 = MM(wh[1][0], h1f[0], bA1);
      bA0 = MM(wh[0][1], h1f[1], bA0); bA1 = MM(wh[1][1], h1f[1], bA1);
      bB0 = MM(wh[0][2], h1f[2], bB0); bB1 = MM(wh[1][2], h1f[2], bB1);
      bB0 = MM(wh[0][3], h1f[3], bB0); bB1 = MM(wh[1][3], h1f[3], bB1);
      // Wih1 on fresh h0'
      bA0 = MM(wi[0][0], h0f[0], bA0); bA1 = MM(wi[1][0], h0f[0], bA1);
      bA0 = MM(wi[0][1], h0f[1], bA0); bA1 = MM(wi[1][1], h0f[1], bA1);
      bB0 = MM(wi[0][2], h0f[2], bB0); bB1 = MM(wi[1][2], h0f[2], bB1);
      bB0 = MM(wi[0][3], h0f[3], bB0); bB1 = MM(wi[1][3], h0f[3], bB1);
      h4v p0, p1;
#pragma unroll
      for (int r = 0; r < 4; ++r) {
        p0[r] = (_Float16)tanh_fast(bA0[r] + bB0[r]);
        p1[r] = (_Float16)tanh_fast(bA1[r] + bB1[r]);
      }
      *(h4v*)&hb1[wofs0] = p0;
      *(h4v*)&hb1[wofs1] = p1;
    }
    BARRIER();  // bar2: h1' visible

    // ---------- Phase C: carry h1' frags; prefetch ep(t+1); FC output ----------
    h1f[0] = *(const h8v*)&hb1[rd];
    h1f[1] = *(const h8v*)&hb1[rd + 4 * HCH];
    h1f[2] = *(const h8v*)&hb1[rd + 8 * HCH];
    h1f[3] = *(const h8v*)&hb1[rd + 12 * HCH];
    epc[0] = *(const f4v*)&embp[xidn * EPW + 32 * w + 4 * lg];
    epc[1] = *(const f4v*)&embp[xidn * EPW + 32 * w + 16 + 4 * lg];
    if (fcact) {
      f4v cA0 = fcv[0], cA1 = fcv[1];
      f4v cB0 = {0.f, 0.f, 0.f, 0.f}, cB1 = {0.f, 0.f, 0.f, 0.f};
      cA0 = MM(wf[0][0], h1f[0], cA0); cA1 = MM(wf[1][0], h1f[0], cA1);
      cA0 = MM(wf[0][1], h1f[1], cA0); cA1 = MM(wf[1][1], h1f[1], cA1);
      cB0 = MM(wf[0][2], h1f[2], cB0); cB1 = MM(wf[1][2], h1f[2], cB1);
      cB0 = MM(wf[0][3], h1f[3], cB0); cB1 = MM(wf[1][3], h1f[3], cB1);
      const long rowb = ((long)(bbase + lm) * T_LEN + t) * VC;
      const f4v s0 = cA0 + cB0;
      const f4v s1 = cA1 + cB1;
      const int v0 = 32 * w + 4 * lg;
      if (f32) {
        *(f4v*)&outf[rowb + v0] = s0;
        *(f4v*)&outf[rowb + v0 + 16] = s1;
      } else {
        us4v u0, u1;
#pragma unroll
        for (int r = 0; r < 4; ++r) { u0[r] = f2bfbits(s0[r]); u1[r] = f2bfbits(s1[r]); }
        *(us4v*)&outu[rowb + v0] = u0;
        *(us4v*)&outu[rowb + v0 + 16] = u1;
      }
    }
    // no barrier: A(t+1)'s hb0 writes ordered vs B(t) reads by bar2(t);
    // C(t)'s hb1 reads drained at bar1(t+1) before B(t+1) overwrites hb1.
  }

  // ---- final hidden state: all waves hold identical frags; wave 0 writes ----
  if (w == 0) {
#pragma unroll
    for (int kt = 0; kt < 4; ++kt)
#pragma unroll
      for (int j = 0; j < 8; ++j) {
        const int k = kt * 32 + lg * 8 + j;
        const float v0 = (float)h0f[kt][j];
        const float v1 = (float)h1f[kt][j];
        const long i0 = HID_OFF + (long)(bbase + lm) * HD + k;
        const long i1 = i0 + (long)B_SZ * HD;
        if (f32) {
          outf[i0] = v0; outf[i1] = v1;
        } else {
          outu[i0] = f2bfbits(v0); outu[i1] = f2bfbits(v1);
        }
      }
  }
}

extern "C" void kernel_launch(void* const* d_in, const int* in_sizes, int n_in,
                              void* d_out, int out_size, void* d_ws, size_t ws_size,
                              hipStream_t stream) {
  const int* x = (const int*)d_in[0];
  const void* emb = d_in[1];
  const void* Wih0 = d_in[2];
  const void* Whh0 = d_in[3];
  const void* bih0 = d_in[4];
  const void* bhh0 = d_in[5];
  const void* Wih1 = d_in[6];
  const void* Whh1 = d_in[7];
  const void* bih1 = d_in[8];
  const void* bhh1 = d_in[9];
  const void* fcW = d_in[10];
  const void* fcb = d_in[11];

  const size_t need = (size_t)VC * HD * sizeof(float);
  if (d_ws != nullptr && ws_size >= need) {
    float* embp = (float*)d_ws;
    embp_kernel<<<VC, HD, 0, stream>>>(emb, Wih0, bih0, bhh0, embp);
    rnn_mfma<true><<<NBLK, NT, 0, stream>>>(x, embp, emb, Wih0, bih0, bhh0,
                                            Whh0, Wih1, Whh1, bih1, bhh1,
                                            fcW, fcb, d_out);
  } else {
    rnn_mfma<false><<<NBLK, NT, 0, stream>>>(x, nullptr, emb, Wih0, bih0, bhh0,
                                             Whh0, Wih1, Whh1, bih1, bhh1,
                                             fcW, fcb, d_out);
  }
}

// Round 3
// 1145.569 us; speedup vs baseline: 2.1648x; 1.3599x over previous
//
#include <hip/hip_runtime.h>
#include <hip/hip_bf16.h>

// 2-layer tanh RNN. B=256, T=1024, H=128, V=96. x int32; float tensors
// runtime-detected fp32 vs bf16.
// d_in: 0:x 1:emb 2:W_ih0 3:W_hh0 4:b_ih0 5:b_hh0 6:W_ih1 7:W_hh1 8:b_ih1
//       9:b_hh1 10:fc_W 11:fc_b
// d_out: out[B*T,96] ++ hidden[2,B,128]
//
// R3: single-barrier software-pipelined step. Phase tt computes
//   h0(tt)   = tanh(ep(tt) + Whh0.h0(tt-1))
//   h1(tt-1) = tanh(b1 + Wih1.h0(tt-1) + Whh1.h1(tt-2))
//   out(tt-2)= fcb + fcW.h1(tt-2)
// All inputs from previous phases (double-buffered LDS) -> one barrier/step,
// three independent MFMA groups, shared frag reads (h0 feeds W0+Wi; h1 feeds
// Wh+FC). Zero in-loop global loads (tokens as LDS bytes, embp fp16 in LDS)
// so stores are never vmcnt-drained. 8 waves x 16 cols = 2 waves/SIMD.

#define B_SZ 256
#define T_LEN 1024
#define HD 128
#define VC 96
#define OUT_MAIN (B_SZ * T_LEN * VC)
#define HID_OFF OUT_MAIN

#define NB 16              // batches per block
#define NBLK (B_SZ / NB)   // 16 blocks
#define NT 512             // threads = 8 waves
#define EPH 136            // embp row stride (halves): spreads gather banks
#define HCH 136            // h chunk stride (halves): conflict-free frag reads

typedef _Float16 h8v __attribute__((ext_vector_type(8)));
typedef _Float16 h4v __attribute__((ext_vector_type(4)));
typedef _Float16 h2v __attribute__((ext_vector_type(2)));
typedef float f4v __attribute__((ext_vector_type(4)));
typedef unsigned short us4v __attribute__((ext_vector_type(4)));

#define MM(A, Bf, C) __builtin_amdgcn_mfma_f32_16x16x32_f16(A, Bf, C, 0, 0, 0)

// LDS-only barrier: drain LDS ops, never vmcnt (output stores stay in flight).
#define BARRIER()                                          \
  do {                                                     \
    asm volatile("s_waitcnt lgkmcnt(0)" ::: "memory");     \
    __builtin_amdgcn_s_barrier();                          \
    asm volatile("" ::: "memory");                         \
  } while (0)

__device__ __forceinline__ float bf2f(__hip_bfloat16 v) { return __bfloat162float(v); }

__device__ __forceinline__ bool detect_f32(const void* emb) {
  const unsigned short* u = (const unsigned short*)emb;
  int hits = 0;
#pragma unroll
  for (int i = 0; i < 128; ++i) hits += (((u[i] >> 7) & 0xFF) >= 127);
  return hits > 2;
}

__device__ __forceinline__ float ldw(const void* p, int i, bool f32) {
  return f32 ? ((const float*)p)[i] : bf2f(((const __hip_bfloat16*)p)[i]);
}

// tanh(x) = 1 - 2/(e^{2x}+1). Branch/NaN-free; saturates correctly.
__device__ __forceinline__ float tanh_fast(float x) {
  float e = __expf(x + x);
  return 1.0f - __fdividef(2.0f, e + 1.0f);
}

// bf16 RNE round to bits (bounded values).
__device__ __forceinline__ unsigned short f2bfbits(float x) {
  unsigned u = __float_as_uint(x);
  unsigned r = (u + 0x7fffu + ((u >> 16) & 1u)) >> 16;
  return (unsigned short)r;
}

__global__ __launch_bounds__(128) void embp_kernel(
    const void* __restrict__ emb, const void* __restrict__ Wih0,
    const void* __restrict__ bih0, const void* __restrict__ bhh0,
    float* __restrict__ embp) {
  const bool f32 = detect_f32(emb);
  __shared__ float ev[HD];
  const int v = blockIdx.x, r = threadIdx.x;
  ev[r] = ldw(emb, v * HD + r, f32);
  __syncthreads();
  float acc = ldw(bih0, r, f32) + ldw(bhh0, r, f32);
#pragma unroll 8
  for (int j = 0; j < HD; ++j) acc += ldw(Wih0, r * HD + j, f32) * ev[j];
  embp[v * HD + r] = acc;
}

// LDS h layout: (batch m, hidden c) at chunk (c>>3)*HCH + m*8 + (c&7).
// Frag read (lane lm=m, lg, K-tile kt): b128 at (kt*4+lg)*HCH + lm*8.
// Write (wave w owns cols 16w..16w+15): b64 at (2w+(lg>>1))*HCH + lm*8 + 4(lg&1).
template <bool USE_WS>
__global__ __launch_bounds__(NT, 2) void rnn_mfma(
    const int* __restrict__ x,
    const float* __restrict__ embp_g,
    const void* __restrict__ emb,
    const void* __restrict__ Wih0,
    const void* __restrict__ bih0,
    const void* __restrict__ bhh0,
    const void* __restrict__ Whh0,
    const void* __restrict__ Wih1,
    const void* __restrict__ Whh1,
    const void* __restrict__ bih1,
    const void* __restrict__ bhh1,
    const void* __restrict__ fcW,
    const void* __restrict__ fcb_g,
    void* __restrict__ out) {
  __shared__ __align__(16) _Float16 embp16[VC * EPH];   // 26112 B
  __shared__ __align__(16) _Float16 hb0[2][16 * HCH];   // 8704 B (double-buf)
  __shared__ __align__(16) _Float16 hb1[2][16 * HCH];   // 8704 B
  __shared__ unsigned char xb8[T_LEN * NB];             // 16384 B  [t*16+m]

  const int tid = threadIdx.x;
  const int lane = tid & 63;
  const int w = tid >> 6;    // wave 0..7: owns hidden/vocab rows 16w..16w+15
  const int lm = lane & 15;  // batch (B-frag col / D col)
  const int lg = lane >> 4;  // k-subchunk / D row group
  const bool f32 = detect_f32(emb);
  const int bbase = blockIdx.x * NB;

  // ---- stage token bytes: xb8[t*16+m] ----
  for (int i = tid; i < NB * T_LEN; i += NT) {
    const int m = i >> 10, t = i & (T_LEN - 1);
    xb8[t * 16 + m] = (unsigned char)x[(bbase + m) * T_LEN + t];
  }

  // ---- stage embp as fp16 (padded stride EPH) ----
  if constexpr (USE_WS) {
    const float2* src = (const float2*)embp_g;
    for (int i = tid; i < VC * 64; i += NT) {  // float-pairs
      const int v = i >> 6, j = i & 63;
      const float2 f = src[i];
      h2v p; p[0] = (_Float16)f.x; p[1] = (_Float16)f.y;
      ((h2v*)embp16)[v * (EPH / 2) + j] = p;
    }
  } else {
    const int r = tid & 127, vg = tid >> 7;  // vg 0..3
    const float bsum = ldw(bih0, r, f32) + ldw(bhh0, r, f32);
    for (int vi = 0; vi < 24; ++vi) {
      const int v = vg * 24 + vi;
      float acc = bsum;
#pragma unroll 8
      for (int k = 0; k < HD; ++k)
        acc += ldw(Wih0, r * HD + k, f32) * ldw(emb, v * HD + k, f32);
      embp16[v * EPH + r] = (_Float16)acc;
    }
  }

  // ---- zero both parities of h buffers (h(-1)=h(-2)=0) ----
  for (int i = tid; i < 2 * 16 * HCH / 2; i += NT) {
    ((unsigned*)hb0)[i] = 0u;
    ((unsigned*)hb1)[i] = 0u;
  }

  const bool fcact = (w < 6);  // FC rows 0..95 on waves 0..5

  // ---- weight A-frags (fp16): row 16w+lm, k = kt*32 + lg*8 + j ----
  h8v w0[4], wi[4], wh[4], wf[4];
  {
    const int n = 16 * w + lm;
#pragma unroll
    for (int kt = 0; kt < 4; ++kt)
#pragma unroll
      for (int j = 0; j < 8; ++j) {
        const int k = kt * 32 + lg * 8 + j;
        w0[kt][j] = (_Float16)ldw(Whh0, n * HD + k, f32);
        wi[kt][j] = (_Float16)ldw(Wih1, n * HD + k, f32);
        wh[kt][j] = (_Float16)ldw(Whh1, n * HD + k, f32);
        wf[kt][j] = (_Float16)(fcact ? ldw(fcW, n * HD + k, f32) : 0.0f);
      }
  }
  // acc element r <-> row c = 16w + 4lg + r
  f4v b1v, fcv;
#pragma unroll
  for (int r = 0; r < 4; ++r) {
    const int c = 16 * w + 4 * lg + r;
    b1v[r] = ldw(bih1, c, f32) + ldw(bhh1, c, f32);
    fcv[r] = fcact ? ldw(fcb_g, c, f32) : 0.0f;
  }

  const int rdb = lg * HCH + lm * 8;                          // + kt*4*HCH
  const int wofs = (2 * w + (lg >> 1)) * HCH + lm * 8 + 4 * (lg & 1);
  const int gofs = 16 * w + 4 * lg;                           // gather col base

  __syncthreads();  // staging visible

  // ---- prologue: ep(0), xid(1) ----
  h4v epc;
  int xcur;
  {
    const int x0 = xb8[0 * 16 + lm];
    xcur = xb8[1 * 16 + lm];
    epc = *(const h4v*)&embp16[x0 * EPH + gofs];
  }

  float* outf = (float*)out;
  unsigned short* outu = (unsigned short*)out;

#pragma unroll 1
  for (int tt = 0; tt < T_LEN + 2; ++tt) {
    const int q = (tt & 1) ^ 1, p = tt & 1;
    // ---- issue all LDS reads up front ----
    h8v h0f[4], h1f[4];
#pragma unroll
    for (int kt = 0; kt < 4; ++kt) {
      h0f[kt] = *(const h8v*)&hb0[q][rdb + kt * 4 * HCH];
      h1f[kt] = *(const h8v*)&hb1[q][rdb + kt * 4 * HCH];
    }
    const int t2 = (tt + 2 < T_LEN) ? tt + 2 : T_LEN - 1;
    const int xnext = xb8[t2 * 16 + lm];                     // xid(tt+2)
    const h4v epn = *(const h4v*)&embp16[xcur * EPH + gofs]; // ep(tt+1)

    // ---- three independent MFMA groups, 2-long chains ----
    f4v a0 = {(float)epc[0], (float)epc[1], (float)epc[2], (float)epc[3]};
    f4v a0b = {0.f, 0.f, 0.f, 0.f};
    f4v a1 = b1v, a1b = {0.f, 0.f, 0.f, 0.f};
    f4v a1c = {0.f, 0.f, 0.f, 0.f}, a1d = {0.f, 0.f, 0.f, 0.f};
    a0  = MM(w0[0], h0f[0], a0);   a1  = MM(wi[0], h0f[0], a1);
    a0  = MM(w0[1], h0f[1], a0);   a1  = MM(wi[1], h0f[1], a1);
    a1c = MM(wh[0], h1f[0], a1c);  a1c = MM(wh[1], h1f[1], a1c);
    a0b = MM(w0[2], h0f[2], a0b);  a1b = MM(wi[2], h0f[2], a1b);
    a0b = MM(w0[3], h0f[3], a0b);  a1b = MM(wi[3], h0f[3], a1b);
    a1d = MM(wh[2], h1f[2], a1d);  a1d = MM(wh[3], h1f[3], a1d);

    f4v a2 = fcv, a2b = {0.f, 0.f, 0.f, 0.f};
    if (fcact) {
      a2  = MM(wf[0], h1f[0], a2);   a2  = MM(wf[1], h1f[1], a2);
      a2b = MM(wf[2], h1f[2], a2b);  a2b = MM(wf[3], h1f[3], a2b);
    }

    // ---- h0(tt) -> hb0[p] (skip tail phases) ----
    if (tt < T_LEN) {
      const f4v s0 = a0 + a0b;
      h4v o;
#pragma unroll
      for (int r = 0; r < 4; ++r) o[r] = (_Float16)tanh_fast(s0[r]);
      *(h4v*)&hb0[p][wofs] = o;
    }
    // ---- h1(tt-1) -> hb1[p] (tt=0 would fake h1(-1)=tanh(b1): keep zeros) ----
    if (tt >= 1 && tt <= T_LEN) {
      const f4v s1 = (a1 + a1b) + (a1c + a1d);
      h4v o;
#pragma unroll
      for (int r = 0; r < 4; ++r) o[r] = (_Float16)tanh_fast(s1[r]);
      *(h4v*)&hb1[p][wofs] = o;
    }
    // ---- out(tt-2) store (never awaited in-loop) ----
    if (tt >= 2 && fcact) {
      const f4v sv = a2 + a2b;
      const long rowb = ((long)(bbase + lm) * T_LEN + (tt - 2)) * VC + gofs;
      if (f32) {
        *(f4v*)&outf[rowb] = sv;
      } else {
        us4v u;
#pragma unroll
        for (int r = 0; r < 4; ++r) u[r] = f2bfbits(sv[r]);
        *(us4v*)&outu[rowb] = u;
      }
    }

    BARRIER();
    epc = epn;
    xcur = xnext;
  }

  // ---- final hidden: h0(T-1) in hb0[(T-1)&1], h1(T-1) in hb1[T&1] ----
  if (tid < 256) {
    const int m = tid >> 4, ch = tid & 15;
    const h8v v0 = *(const h8v*)&hb0[(T_LEN - 1) & 1][ch * HCH + m * 8];
    const h8v v1 = *(const h8v*)&hb1[T_LEN & 1][ch * HCH + m * 8];
    const long i0 = HID_OFF + (long)(bbase + m) * HD + ch * 8;
    const long i1 = i0 + (long)B_SZ * HD;
    if (f32) {
#pragma unroll
      for (int j = 0; j < 8; ++j) {
        outf[i0 + j] = (float)v0[j];
        outf[i1 + j] = (float)v1[j];
      }
    } else {
#pragma unroll
      for (int j = 0; j < 8; ++j) {
        outu[i0 + j] = f2bfbits((float)v0[j]);
        outu[i1 + j] = f2bfbits((float)v1[j]);
      }
    }
  }
}

extern "C" void kernel_launch(void* const* d_in, const int* in_sizes, int n_in,
                              void* d_out, int out_size, void* d_ws, size_t ws_size,
                              hipStream_t stream) {
  const int* x = (const int*)d_in[0];
  const void* emb = d_in[1];
  const void* Wih0 = d_in[2];
  const void* Whh0 = d_in[3];
  const void* bih0 = d_in[4];
  const void* bhh0 = d_in[5];
  const void* Wih1 = d_in[6];
  const void* Whh1 = d_in[7];
  const void* bih1 = d_in[8];
  const void* bhh1 = d_in[9];
  const void* fcW = d_in[10];
  const void* fcb = d_in[11];

  const size_t need = (size_t)VC * HD * sizeof(float);
  if (d_ws != nullptr && ws_size >= need) {
    float* embp = (float*)d_ws;
    embp_kernel<<<VC, HD, 0, stream>>>(emb, Wih0, bih0, bhh0, embp);
    rnn_mfma<true><<<NBLK, NT, 0, stream>>>(x, embp, emb, Wih0, bih0, bhh0,
                                            Whh0, Wih1, Whh1, bih1, bhh1,
                                            fcW, fcb, d_out);
  } else {
    rnn_mfma<false><<<NBLK, NT, 0, stream>>>(x, nullptr, emb, Wih0, bih0, bhh0,
                                             Whh0, Wih1, Whh1, bih1, bhh1,
                                             fcW, fcb, d_out);
  }
}